// Round 8
// baseline (436.343 us; speedup 1.0000x reference)
//
#include <hip/hip_runtime.h>
#include <hip/hip_bf16.h>

// GCN 3-layer forward on MI355X — round 8.
//  * Feature-sliced aggregation: gather tables stored [slice][N][16] fp16
//    (3.2MB/slice <= 4MB XCD L2). blockIdx.y = slice phases the grid so all
//    XCDs work one slice at a time -> gathers become L2-resident.
//    Layer-2 agg: 8 slices; layer-1 agg: 4 slices. col nt-loaded (streaming).
//  * MFMA kernels read/write sliced layouts directly (index remap only).
//  * Softmax layer agg stays row-major + fused (needs whole row).
//  * prep_w merged into prescale; scan_part folded into scan_apply: 11 launches.

#define NB1 256  // level-1 blocks for hist/scatter

typedef __attribute__((ext_vector_type(4))) _Float16 half4;
typedef __attribute__((ext_vector_type(8))) _Float16 half8;
typedef __attribute__((ext_vector_type(4))) float f32x4;

// ---------------- CSR build (atomic-free, 2-level) ----------------

__global__ __launch_bounds__(256) void k_hist(const int* __restrict__ dst, int E, int C,
                                              int NBUK, int* __restrict__ gh) {
  __shared__ int h[512];
  int t = threadIdx.x, b = blockIdx.x;
  for (int i = t; i < NBUK; i += 256) h[i] = 0;
  __syncthreads();
  int beg = b * C, end = min(beg + C, E);
  for (int i = beg + t; i < end; i += 256) atomicAdd(&h[dst[i] >> 8], 1);
  __syncthreads();
  for (int i = t; i < NBUK; i += 256) gh[i * NB1 + b] = h[i];
}

__global__ __launch_bounds__(256) void k_sum256(const int* __restrict__ g, int L,
                                                int* __restrict__ part) {
  __shared__ int red[256];
  int t = threadIdx.x;
  int idx = blockIdx.x * 256 + t;
  red[t] = (idx < L) ? g[idx] : 0;
  __syncthreads();
  for (int off = 128; off > 0; off >>= 1) {
    if (t < off) red[t] += red[t + off];
    __syncthreads();
  }
  if (t == 0) part[blockIdx.x] = red[0];
}

// merged: per-block computes its own prefix over part[] then scans its chunk
__global__ __launch_bounds__(256) void k_scan_apply(const int* __restrict__ g, int L,
                                                    const int* __restrict__ part, int NP,
                                                    int* __restrict__ gout) {
  __shared__ int pl[512];
  __shared__ int sh[256];
  int t = threadIdx.x, bid = blockIdx.x;
  pl[t] = (t < NP) ? part[t] : 0;
  pl[t + 256] = (t + 256 < NP) ? part[t + 256] : 0;
  __syncthreads();
  int partial = 0;
  for (int i = t; i < bid; i += 256) partial += pl[i];
  sh[t] = partial;
  __syncthreads();
  for (int off = 128; off > 0; off >>= 1) {
    if (t < off) sh[t] += sh[t + off];
    __syncthreads();
  }
  int pre = sh[0];
  __syncthreads();
  int idx = bid * 256 + t;
  int v = (idx < L) ? g[idx] : 0;
  sh[t] = v;
  __syncthreads();
  for (int off = 1; off < 256; off <<= 1) {
    int u = (t >= off) ? sh[t - off] : 0;
    __syncthreads();
    sh[t] += u;
    __syncthreads();
  }
  if (idx < L) gout[idx] = pre + sh[t] - v;
}

// payload: src | (dst&255)<<24  (src < 2^17)
__global__ __launch_bounds__(256) void k_scatter(const int* __restrict__ src,
                                                 const int* __restrict__ dst, int E, int C,
                                                 int NBUK, const int* __restrict__ gscan,
                                                 int* __restrict__ epak) {
  __shared__ int cur[512];
  int t = threadIdx.x, b = blockIdx.x;
  for (int i = t; i < NBUK; i += 256) cur[i] = gscan[i * NB1 + b];
  __syncthreads();
  int beg = b * C, end = min(beg + C, E);
  for (int i = beg + t; i < end; i += 256) {
    int d = dst[i];
    int p = atomicAdd(&cur[d >> 8], 1);
    epak[p] = src[i] | ((d & 255) << 24);
  }
}

__global__ __launch_bounds__(256) void k_csr(const int* __restrict__ epak,
                                             const int* __restrict__ gscan, int NBUK, int N, int E,
                                             int* __restrict__ rowptr, float* __restrict__ dinv,
                                             int* __restrict__ col) {
  __shared__ int cnt[256];
  __shared__ int scn[256];
  __shared__ int cur[256];
  int b = blockIdx.x, t = threadIdx.x;
  int ebeg = gscan[b * NB1];
  int eend = (b + 1 < NBUK) ? gscan[(b + 1) * NB1] : E;
  cnt[t] = 0;
  __syncthreads();
  for (int i = ebeg + t; i < eend; i += 256) atomicAdd(&cnt[(epak[i] >> 24) & 255], 1);
  __syncthreads();
  int c = cnt[t];
  scn[t] = c;
  __syncthreads();
  for (int off = 1; off < 256; off <<= 1) {
    int v = (t >= off) ? scn[t - off] : 0;
    __syncthreads();
    scn[t] += v;
    __syncthreads();
  }
  int excl = scn[t] - c;
  int node = b * 256 + t;
  if (node < N) {
    rowptr[node] = ebeg + excl;
    dinv[node] = rsqrtf((float)(c + 1));  // +1 self-loop
  }
  cur[t] = ebeg + excl;
  __syncthreads();
  for (int i = ebeg + t; i < eend; i += 256) {
    int e = epak[i];
    int p = atomicAdd(&cur[(e >> 24) & 255], 1);
    col[p] = e & 0xFFFFFF;
  }
  if (b == 0 && t == 0) rowptr[N] = E;
}

// ---------------- prep: sliced prescale of x + fp16 weight conversion ----------------
// hx_s layout [4][N][16]; blocks >= PRE convert weights.
__global__ __launch_bounds__(256) void k_prep(const float* __restrict__ x,
                                              const float* __restrict__ dinv,
                                              const float* __restrict__ W1,
                                              const float* __restrict__ W2,
                                              const float* __restrict__ W3,
                                              _Float16* __restrict__ hx_s,
                                              _Float16* __restrict__ w1h,
                                              _Float16* __restrict__ w2h,
                                              _Float16* __restrict__ w3h, int N, int PRE) {
  int t = threadIdx.x;
  if ((int)blockIdx.x >= PRE) {
    int i = ((int)blockIdx.x - PRE) * 256 + t;
    if (i < 128 * 64) w1h[i] = (_Float16)W1[i];
    if (i < 128 * 128) w2h[i] = (_Float16)W2[i];
    if (i < 64 * 128) w3h[i] = (_Float16)W3[i];
    return;
  }
  __shared__ float xl[32 * 64];
  int rbase = blockIdx.x * 32;
  const float4* xp = (const float4*)&x[(size_t)rbase * 64];
  ((float4*)xl)[t] = xp[t];
  ((float4*)xl)[t + 256] = xp[t + 256];
  __syncthreads();
  int slice = t >> 6, rem = t & 63, ri = rem >> 1, fo = (rem & 1) * 8;
  int r = rbase + ri;
  float d = dinv[r];
  half8 o;
#pragma unroll
  for (int k = 0; k < 8; ++k) o[k] = (_Float16)(xl[ri * 64 + slice * 16 + fo + k] * d);
  *(half8*)&hx_s[((size_t)slice * N + r) * 16 + fo] = o;
}

// ---------------- sliced aggregation ----------------
// tin/tout: [NS][N][16] fp16 (values pre-scaled by dinv).
// out_slice[r] = dinv[r] * (sum_{src} tin_s[src] + tin_s[r]).
// Wave: 4 rows x (8 edge-groups x 2 feat-lanes). blockIdx.y = slice (phased).
template <int NS>
__global__ __launch_bounds__(256) void k_aggs(const _Float16* __restrict__ tin,
                                              const float* __restrict__ dinv,
                                              const int* __restrict__ rowptr,
                                              const int* __restrict__ col,
                                              _Float16* __restrict__ tout, int N) {
  int slice = blockIdx.y;
  int wave = threadIdx.x >> 6, lane = threadIdx.x & 63;
  int r = blockIdx.x * 16 + wave * 4 + (lane >> 4);
  if (r >= N) return;
  int eg = (lane >> 1) & 7;
  int fo = (lane & 1) * 8;
  const _Float16* ts = tin + (size_t)slice * N * 16;
  float acc[8] = {0.f, 0.f, 0.f, 0.f, 0.f, 0.f, 0.f, 0.f};
  int r0 = rowptr[r], r1 = rowptr[r + 1];
  for (int base = r0; base < r1; base += 8) {
    int e = base + eg;
    int ec = (e < r1) ? e : r0;  // r0 valid whenever loop runs
    int s = __builtin_nontemporal_load(&col[ec]);
    half8 v = *(const half8*)&ts[(size_t)s * 16 + fo];
    if (e < r1) {
#pragma unroll
      for (int k = 0; k < 8; ++k) acc[k] += (float)v[k];
    }
  }
#pragma unroll
  for (int o = 2; o <= 8; o <<= 1) {
#pragma unroll
    for (int k = 0; k < 8; ++k) acc[k] += __shfl_xor(acc[k], o);
  }
  if (eg == 0) {
    half8 sv = *(const half8*)&ts[(size_t)r * 16 + fo];
    float di = dinv[r];
    half8 o;
#pragma unroll
    for (int k = 0; k < 8; ++k) o[k] = (_Float16)(di * (acc[k] + (float)sv[k]));
    *(half8*)&tout[((size_t)slice * N + r) * 16 + fo] = o;
  }
}

// ---------------- final aggregation + softmax (row-major hz [N][64]) ----------------
__global__ __launch_bounds__(256) void k_agg64f(const _Float16* __restrict__ hp,
                                                const float* __restrict__ dinv,
                                                const int* __restrict__ rowptr,
                                                const int* __restrict__ col,
                                                const float* __restrict__ bias,
                                                float* __restrict__ out, int N) {
  int wid = blockIdx.x * 4 + (threadIdx.x >> 6);
  int lane = threadIdx.x & 63;
  if (wid >= N) return;
  int g = lane >> 3;
  int fl = (lane & 7) * 8;
  float acc[8] = {0.f, 0.f, 0.f, 0.f, 0.f, 0.f, 0.f, 0.f};
  int r0 = rowptr[wid], r1 = rowptr[wid + 1];
  for (int base = r0; base < r1; base += 64) {
    int mm = min(64, r1 - base);
    int ce = (base + lane < r1) ? col[base + lane] : 0;
    for (int j = 0; j < mm; j += 16) {
      int i0 = j + g, i1 = j + 8 + g;
      int s0 = __shfl(ce, i0);
      int s1 = __shfl(ce, i1);
      if (i0 < mm) {
        half8 v = *(const half8*)&hp[(size_t)s0 * 64 + fl];
#pragma unroll
        for (int k = 0; k < 8; ++k) acc[k] += (float)v[k];
      }
      if (i1 < mm) {
        half8 v = *(const half8*)&hp[(size_t)s1 * 64 + fl];
#pragma unroll
        for (int k = 0; k < 8; ++k) acc[k] += (float)v[k];
      }
    }
  }
#pragma unroll
  for (int o = 8; o < 64; o <<= 1) {
#pragma unroll
    for (int k = 0; k < 8; ++k) acc[k] += __shfl_xor(acc[k], o);
  }
  half8 sv = *(const half8*)&hp[(size_t)wid * 64 + fl];
  float di = dinv[wid];
  float v[8];
#pragma unroll
  for (int k = 0; k < 8; ++k) v[k] = di * (acc[k] + (float)sv[k]);
  float4 ba = *(const float4*)&bias[fl];
  float4 bb = *(const float4*)&bias[fl + 4];
  v[0] += ba.x; v[1] += ba.y; v[2] += ba.z; v[3] += ba.w;
  v[4] += bb.x; v[5] += bb.y; v[6] += bb.z; v[7] += bb.w;
  float mx = v[0];
#pragma unroll
  for (int k = 1; k < 8; ++k) mx = fmaxf(mx, v[k]);
#pragma unroll
  for (int o = 1; o < 8; o <<= 1) mx = fmaxf(mx, __shfl_xor(mx, o));
  float s = 0.f;
#pragma unroll
  for (int k = 0; k < 8; ++k) {
    v[k] = expf(v[k] - mx);
    s += v[k];
  }
#pragma unroll
  for (int o = 1; o < 8; o <<= 1) s += __shfl_xor(s, o);
  float inv = 1.0f / s;
#pragma unroll
  for (int k = 0; k < 8; ++k) v[k] *= inv;
  if (lane < 8) {
    float4 o0 = make_float4(v[0], v[1], v[2], v[3]);
    float4 o1 = make_float4(v[4], v[5], v[6], v[7]);
    *(float4*)&out[(size_t)wid * 64 + fl] = o0;
    *(float4*)&out[(size_t)wid * 64 + fl + 4] = o1;
  }
}

// ---------------- MFMA layer kernels (sliced I/O layouts) ----------------
// W-frag as A operand, row-frag as B: D(lane) = row rb+(lane&15),
// cols nt*16 + (lane>>4)*4 + reg.

// h1s[8][N][16] = (half) dinv * relu(A1s @ W1^T + b1);  A1s = a1s[4][N][16]
__global__ __launch_bounds__(256) void k_mfma1(const _Float16* __restrict__ a1s,
                                               const _Float16* __restrict__ w1h,  // [128][64]
                                               const float* __restrict__ b1,
                                               const float* __restrict__ dinv,
                                               _Float16* __restrict__ h1s, int N) {
  int wave = threadIdx.x >> 6, lane = threadIdx.x & 63;
  int rb = blockIdx.x * 128 + wave * 32;
  if (rb >= N) return;
  int lrow = lane & 15, lg = lane >> 4;

  half8 arow[2][2];
#pragma unroll
  for (int rt = 0; rt < 2; ++rt) {
    int r = rb + rt * 16 + lrow;
    if (r >= N) r = N - 1;
#pragma unroll
    for (int ks = 0; ks < 2; ++ks)
      arow[rt][ks] = *(const half8*)&a1s[((size_t)(2 * ks + (lg >> 1)) * N + r) * 16 + (lg & 1) * 8];
  }
  f32x4 acc[2][8];
#pragma unroll
  for (int rt = 0; rt < 2; ++rt)
#pragma unroll
    for (int nt = 0; nt < 8; ++nt) acc[rt][nt] = (f32x4){0.f, 0.f, 0.f, 0.f};

#pragma unroll
  for (int nt = 0; nt < 8; ++nt) {
#pragma unroll
    for (int ks = 0; ks < 2; ++ks) {
      half8 wf = *(const half8*)&w1h[(size_t)(nt * 16 + lrow) * 64 + ks * 32 + lg * 8];
      acc[0][nt] = __builtin_amdgcn_mfma_f32_16x16x32_f16(wf, arow[0][ks], acc[0][nt], 0, 0, 0);
      acc[1][nt] = __builtin_amdgcn_mfma_f32_16x16x32_f16(wf, arow[1][ks], acc[1][nt], 0, 0, 0);
    }
  }
#pragma unroll
  for (int rt = 0; rt < 2; ++rt) {
    int r = rb + rt * 16 + lrow;
    if (r < N) {
      float di = dinv[r];
#pragma unroll
      for (int nt = 0; nt < 8; ++nt) {
        int n = nt * 16 + lg * 4;
        float4 bb = *(const float4*)&b1[n];
        half4 o;
        o[0] = (_Float16)(fmaxf(acc[rt][nt][0] + bb.x, 0.f) * di);
        o[1] = (_Float16)(fmaxf(acc[rt][nt][1] + bb.y, 0.f) * di);
        o[2] = (_Float16)(fmaxf(acc[rt][nt][2] + bb.z, 0.f) * di);
        o[3] = (_Float16)(fmaxf(acc[rt][nt][3] + bb.w, 0.f) * di);
        *(half4*)&h1s[((size_t)nt * N + r) * 16 + lg * 4] = o;
      }
    }
  }
}

// hz[N][64] = (half) dinv * ( relu(A2s @ W2^T + b2) @ W3^T );  A2s = a2s[8][N][16]
__global__ __launch_bounds__(256) void k_mfma23(const _Float16* __restrict__ a2s,
                                                const _Float16* __restrict__ w2h,  // [128][128]
                                                const float* __restrict__ b2,
                                                const _Float16* __restrict__ w3h,  // [64][128]
                                                const float* __restrict__ dinv,
                                                _Float16* __restrict__ hz, int N) {
  __shared__ _Float16 u_lds[4][32][136];
  int wave = threadIdx.x >> 6, lane = threadIdx.x & 63;
  int rb = blockIdx.x * 128 + wave * 32;
  if (rb >= N) return;
  int lrow = lane & 15, lg = lane >> 4;

  half8 frag[2][4];
#pragma unroll
  for (int rt = 0; rt < 2; ++rt) {
    int r = rb + rt * 16 + lrow;
    if (r >= N) r = N - 1;
#pragma unroll
    for (int ks = 0; ks < 4; ++ks)
      frag[rt][ks] = *(const half8*)&a2s[((size_t)(2 * ks + (lg >> 1)) * N + r) * 16 + (lg & 1) * 8];
  }
  f32x4 acc[2][8];
#pragma unroll
  for (int rt = 0; rt < 2; ++rt)
#pragma unroll
    for (int nt = 0; nt < 8; ++nt) acc[rt][nt] = (f32x4){0.f, 0.f, 0.f, 0.f};

#pragma unroll
  for (int nt = 0; nt < 8; ++nt) {
#pragma unroll
    for (int ks = 0; ks < 4; ++ks) {
      half8 wf = *(const half8*)&w2h[(size_t)(nt * 16 + lrow) * 128 + ks * 32 + lg * 8];
      acc[0][nt] = __builtin_amdgcn_mfma_f32_16x16x32_f16(wf, frag[0][ks], acc[0][nt], 0, 0, 0);
      acc[1][nt] = __builtin_amdgcn_mfma_f32_16x16x32_f16(wf, frag[1][ks], acc[1][nt], 0, 0, 0);
    }
  }
#pragma unroll
  for (int rt = 0; rt < 2; ++rt) {
#pragma unroll
    for (int nt = 0; nt < 8; ++nt) {
      int n = nt * 16 + lg * 4;
      float4 bb = *(const float4*)&b2[n];
      half4 o;
      o[0] = (_Float16)fmaxf(acc[rt][nt][0] + bb.x, 0.f);
      o[1] = (_Float16)fmaxf(acc[rt][nt][1] + bb.y, 0.f);
      o[2] = (_Float16)fmaxf(acc[rt][nt][2] + bb.z, 0.f);
      o[3] = (_Float16)fmaxf(acc[rt][nt][3] + bb.w, 0.f);
      *(half4*)&u_lds[wave][rt * 16 + lrow][n] = o;
    }
  }
#pragma unroll
  for (int rt = 0; rt < 2; ++rt)
#pragma unroll
    for (int ks = 0; ks < 4; ++ks)
      frag[rt][ks] = *(const half8*)&u_lds[wave][rt * 16 + lrow][ks * 32 + lg * 8];

  f32x4 acc2[2][4];
#pragma unroll
  for (int rt = 0; rt < 2; ++rt)
#pragma unroll
    for (int mt = 0; mt < 4; ++mt) acc2[rt][mt] = (f32x4){0.f, 0.f, 0.f, 0.f};

#pragma unroll
  for (int mt = 0; mt < 4; ++mt) {
#pragma unroll
    for (int ks = 0; ks < 4; ++ks) {
      half8 wf = *(const half8*)&w3h[(size_t)(mt * 16 + lrow) * 128 + ks * 32 + lg * 8];
      acc2[0][mt] = __builtin_amdgcn_mfma_f32_16x16x32_f16(wf, frag[0][ks], acc2[0][mt], 0, 0, 0);
      acc2[1][mt] = __builtin_amdgcn_mfma_f32_16x16x32_f16(wf, frag[1][ks], acc2[1][mt], 0, 0, 0);
    }
  }
#pragma unroll
  for (int rt = 0; rt < 2; ++rt) {
    int r = rb + rt * 16 + lrow;
    if (r < N) {
      float di = dinv[r];
#pragma unroll
      for (int mt = 0; mt < 4; ++mt) {
        int m = mt * 16 + lg * 4;
        half4 o;
        o[0] = (_Float16)(acc2[rt][mt][0] * di);
        o[1] = (_Float16)(acc2[rt][mt][1] * di);
        o[2] = (_Float16)(acc2[rt][mt][2] * di);
        o[3] = (_Float16)(acc2[rt][mt][3] * di);
        *(half4*)&hz[(size_t)r * 64 + m] = o;
      }
    }
  }
}

// ---------------- launch ----------------

extern "C" void kernel_launch(void* const* d_in, const int* in_sizes, int n_in,
                              void* d_out, int out_size, void* d_ws, size_t ws_size,
                              hipStream_t stream) {
  const float* x  = (const float*)d_in[0];
  const int*   ei = (const int*)d_in[1];
  const float* W1 = (const float*)d_in[2];
  const float* b1 = (const float*)d_in[3];
  const float* W2 = (const float*)d_in[4];
  const float* b2 = (const float*)d_in[5];
  const float* W3 = (const float*)d_in[6];
  const float* b3 = (const float*)d_in[7];
  float* out = (float*)d_out;

  const int N = in_sizes[0] / 64;
  const int E = in_sizes[1] / 2;
  const int* esrc = ei;
  const int* edst = ei + E;

  const int NBUK = (N + 255) / 256;
  const int C1 = (E + NB1 - 1) / NB1;
  const int L = NBUK * NB1;
  const int NA = (L + 255) / 256;

  char* w = (char*)d_ws;
  auto take = [&](size_t bytes) -> void* {
    void* p = (void*)w;
    w += (bytes + 255) & ~(size_t)255;
    return p;
  };
  int*   rowptr = (int*)take((size_t)(N + 1) * 4);
  float* dinv   = (float*)take((size_t)N * 4);
  int*   col    = (int*)take((size_t)E * 4);
  int*   gh     = (int*)take((size_t)L * 4);
  int*   gscan  = (int*)take((size_t)L * 4);
  int*   part   = (int*)take((size_t)NA * 4);
  _Float16* w1h = (_Float16*)take((size_t)128 * 64 * 2);
  _Float16* w2h = (_Float16*)take((size_t)128 * 128 * 2);
  _Float16* w3h = (_Float16*)take((size_t)64 * 128 * 2);
  _Float16* hx_s = (_Float16*)take((size_t)4 * N * 16 * 2);   // sliced x; reused as hz
  _Float16* a1s  = (_Float16*)take((size_t)4 * N * 16 * 2);   // sliced agg(x)
  _Float16* h1s  = (_Float16*)take((size_t)8 * N * 16 * 2);   // sliced h1; epak aliases
  _Float16* a2s  = (_Float16*)take((size_t)8 * N * 16 * 2);   // sliced agg(h1)
  int*   epak   = (int*)h1s;  // dead before h1s's first write
  _Float16* hz  = hx_s;       // x slices dead after layer-1 agg

  // CSR build (no global atomics)
  k_hist<<<NB1, 256, 0, stream>>>(edst, E, C1, NBUK, gh);
  k_sum256<<<NA, 256, 0, stream>>>(gh, L, part);
  k_scan_apply<<<NA, 256, 0, stream>>>(gh, L, part, NA, gscan);
  k_scatter<<<NB1, 256, 0, stream>>>(esrc, edst, E, C1, NBUK, gscan, epak);
  k_csr<<<NBUK, 256, 0, stream>>>(epak, gscan, NBUK, N, E, rowptr, dinv, col);

  // prescale (sliced) + weight fp16 conversion
  const int PRE = (N + 31) / 32;
  k_prep<<<PRE + 128, 256, 0, stream>>>(x, dinv, W1, W2, W3, hx_s, w1h, w2h, w3h, N, PRE);

  const int rowblocks = (N + 15) / 16;
  const int mfmablocks = (N + 127) / 128;

  // A1s = agg(hx_s)          [4 slices]
  k_aggs<4><<<dim3(rowblocks, 4), 256, 0, stream>>>(hx_s, dinv, rowptr, col, a1s, N);
  // h1s = dinv * relu(A1s @ W1^T + b1)
  k_mfma1<<<mfmablocks, 256, 0, stream>>>(a1s, w1h, b1, dinv, h1s, N);
  // A2s = agg(h1s)           [8 slices]
  k_aggs<8><<<dim3(rowblocks, 8), 256, 0, stream>>>(h1s, dinv, rowptr, col, a2s, N);
  // hz = dinv * (relu(A2s @ W2^T + b2) @ W3^T)   [row-major]
  k_mfma23<<<mfmablocks, 256, 0, stream>>>(a2s, w2h, b2, w3h, dinv, hz, N);
  // out = softmax(agg(hz) + b3)
  k_agg64f<<<(N + 3) / 4, 256, 0, stream>>>(hz, dinv, rowptr, col, b3, out, N);
}

// Round 9
// 358.720 us; speedup vs baseline: 1.2164x; 1.2164x over previous
//
#include <hip/hip_runtime.h>
#include <hip/hip_bf16.h>

// GCN 3-layer forward on MI355X — round 9.
//  * REVERT round-8 feature slicing (regressed: 32B sliced rows waste half of
//    each 64B line and break request coalescing; row-major 256B/128B coalesced
//    row gathers are strictly better). Back to round-7 agg structure.
//  * Agg inner loops unrolled 4x: 16 edges in flight per wave (was 8) — the
//    gather ran at 3.5 of ~6.3 TB/s, partially latency-bound.
//  * Launches 13 -> 10: weights fp16 conversion folded into k_hist's spare
//    blocks; scan_part merged into scan_apply (r8); x-prescale folded into
//    k_csr's tail (block owns nodes of its bucket; dinv already in registers).

#define NB1 256  // level-1 blocks for hist/scatter

typedef __attribute__((ext_vector_type(4))) _Float16 half4;
typedef __attribute__((ext_vector_type(8))) _Float16 half8;
typedef __attribute__((ext_vector_type(4))) float f32x4;

// ---------------- CSR build (atomic-free, 2-level) + fused extras ----------------

// blocks [0,NB1): histogram by dst>>8.  blocks [NB1, NB1+128): weights -> fp16.
__global__ __launch_bounds__(256) void k_hist(const int* __restrict__ dst, int E, int C,
                                              int NBUK, int* __restrict__ gh,
                                              const float* __restrict__ W1,
                                              const float* __restrict__ W2,
                                              const float* __restrict__ W3,
                                              _Float16* __restrict__ w1h,
                                              _Float16* __restrict__ w2h,
                                              _Float16* __restrict__ w3h) {
  int t = threadIdx.x, b = blockIdx.x;
  if (b >= NB1) {
    int i = (b - NB1) * 256 + t;
    if (i < 128 * 64) w1h[i] = (_Float16)W1[i];
    if (i < 128 * 128) w2h[i] = (_Float16)W2[i];
    if (i < 64 * 128) w3h[i] = (_Float16)W3[i];
    return;
  }
  __shared__ int h[512];
  for (int i = t; i < NBUK; i += 256) h[i] = 0;
  __syncthreads();
  int beg = b * C, end = min(beg + C, E);
  for (int i = beg + t; i < end; i += 256) atomicAdd(&h[dst[i] >> 8], 1);
  __syncthreads();
  for (int i = t; i < NBUK; i += 256) gh[i * NB1 + b] = h[i];
}

__global__ __launch_bounds__(256) void k_sum256(const int* __restrict__ g, int L,
                                                int* __restrict__ part) {
  __shared__ int red[256];
  int t = threadIdx.x;
  int idx = blockIdx.x * 256 + t;
  red[t] = (idx < L) ? g[idx] : 0;
  __syncthreads();
  for (int off = 128; off > 0; off >>= 1) {
    if (t < off) red[t] += red[t + off];
    __syncthreads();
  }
  if (t == 0) part[blockIdx.x] = red[0];
}

// merged: per-block computes its own prefix over part[] then scans its chunk
__global__ __launch_bounds__(256) void k_scan_apply(const int* __restrict__ g, int L,
                                                    const int* __restrict__ part, int NP,
                                                    int* __restrict__ gout) {
  __shared__ int pl[512];
  __shared__ int sh[256];
  int t = threadIdx.x, bid = blockIdx.x;
  pl[t] = (t < NP) ? part[t] : 0;
  pl[t + 256] = (t + 256 < NP) ? part[t + 256] : 0;
  __syncthreads();
  int partial = 0;
  for (int i = t; i < bid; i += 256) partial += pl[i];
  sh[t] = partial;
  __syncthreads();
  for (int off = 128; off > 0; off >>= 1) {
    if (t < off) sh[t] += sh[t + off];
    __syncthreads();
  }
  int pre = sh[0];
  __syncthreads();
  int idx = bid * 256 + t;
  int v = (idx < L) ? g[idx] : 0;
  sh[t] = v;
  __syncthreads();
  for (int off = 1; off < 256; off <<= 1) {
    int u = (t >= off) ? sh[t - off] : 0;
    __syncthreads();
    sh[t] += u;
    __syncthreads();
  }
  if (idx < L) gout[idx] = pre + sh[t] - v;
}

// payload: src | (dst&255)<<24  (src < 2^17)
__global__ __launch_bounds__(256) void k_scatter(const int* __restrict__ src,
                                                 const int* __restrict__ dst, int E, int C,
                                                 int NBUK, const int* __restrict__ gscan,
                                                 int* __restrict__ epak) {
  __shared__ int cur[512];
  int t = threadIdx.x, b = blockIdx.x;
  for (int i = t; i < NBUK; i += 256) cur[i] = gscan[i * NB1 + b];
  __syncthreads();
  int beg = b * C, end = min(beg + C, E);
  for (int i = beg + t; i < end; i += 256) {
    int d = dst[i];
    int p = atomicAdd(&cur[d >> 8], 1);
    epak[p] = src[i] | ((d & 255) << 24);
  }
}

// per-bucket exact CSR + dinv; tail: prescale x rows of this bucket -> hx fp16.
__global__ __launch_bounds__(256) void k_csr(const int* __restrict__ epak,
                                             const int* __restrict__ gscan, int NBUK, int N, int E,
                                             int* __restrict__ rowptr, float* __restrict__ dinv,
                                             int* __restrict__ col,
                                             const float* __restrict__ x,
                                             _Float16* __restrict__ hx) {
  __shared__ int cnt[256];
  __shared__ int scn[256];
  __shared__ int cur[256];
  int b = blockIdx.x, t = threadIdx.x;
  int ebeg = gscan[b * NB1];
  int eend = (b + 1 < NBUK) ? gscan[(b + 1) * NB1] : E;
  cnt[t] = 0;
  __syncthreads();
  for (int i = ebeg + t; i < eend; i += 256) atomicAdd(&cnt[(epak[i] >> 24) & 255], 1);
  __syncthreads();
  int c = cnt[t];
  scn[t] = c;
  __syncthreads();
  for (int off = 1; off < 256; off <<= 1) {
    int v = (t >= off) ? scn[t - off] : 0;
    __syncthreads();
    scn[t] += v;
    __syncthreads();
  }
  int excl = scn[t] - c;
  int node = b * 256 + t;
  float d = rsqrtf((float)(c + 1));  // +1 self-loop
  if (node < N) {
    rowptr[node] = ebeg + excl;
    dinv[node] = d;
  }
  cur[t] = ebeg + excl;
  __syncthreads();
  for (int i = ebeg + t; i < eend; i += 256) {
    int e = epak[i];
    int p = atomicAdd(&cur[(e >> 24) & 255], 1);
    col[p] = e & 0xFFFFFF;
  }
  if (b == 0 && t == 0) rowptr[N] = E;
  // prescale tail: hx[node] = (half)(d * x[node])
  if (node < N) {
    const float4* xr = (const float4*)&x[(size_t)node * 64];
    half8* hr = (half8*)&hx[(size_t)node * 64];
#pragma unroll
    for (int q = 0; q < 8; ++q) {
      float4 a = xr[q * 2], bb = xr[q * 2 + 1];
      half8 o;
      o[0] = (_Float16)(a.x * d); o[1] = (_Float16)(a.y * d);
      o[2] = (_Float16)(a.z * d); o[3] = (_Float16)(a.w * d);
      o[4] = (_Float16)(bb.x * d); o[5] = (_Float16)(bb.y * d);
      o[6] = (_Float16)(bb.z * d); o[7] = (_Float16)(bb.w * d);
      hr[q] = o;
    }
  }
}

// ---------------- aggregation (pull, 1 row/wave, fp16 row-major tables) ----------------
// input hp pre-scaled by dinv; result = dinv[r] * (sum_nbrs hp[s] + hp[r]).
// EPI 0: write fp16 table. EPI 1: +bias, softmax, write f32 output.

template <int EPI>
__global__ __launch_bounds__(256) void k_agg64h(const _Float16* __restrict__ hp,
                                                const float* __restrict__ dinv,
                                                const int* __restrict__ rowptr,
                                                const int* __restrict__ col,
                                                const float* __restrict__ bias,
                                                void* __restrict__ outp, int N) {
  int wid = blockIdx.x * 4 + (threadIdx.x >> 6);
  int lane = threadIdx.x & 63;
  if (wid >= N) return;
  int g = lane >> 3;
  int fl = (lane & 7) * 8;
  float acc[8] = {0.f, 0.f, 0.f, 0.f, 0.f, 0.f, 0.f, 0.f};
  int r0 = rowptr[wid], r1 = rowptr[wid + 1];
  for (int base = r0; base < r1; base += 64) {
    int mm = min(64, r1 - base);
    int ce = (base + lane < r1) ? col[base + lane] : 0;
    for (int j = 0; j < mm; j += 32) {
      int i0 = j + g, i1 = j + 8 + g, i2 = j + 16 + g, i3 = j + 24 + g;
      int s0 = __shfl(ce, i0), s1 = __shfl(ce, i1);
      int s2 = __shfl(ce, i2), s3 = __shfl(ce, i3);
      if (i0 < mm) {
        half8 v = *(const half8*)&hp[(size_t)s0 * 64 + fl];
#pragma unroll
        for (int k = 0; k < 8; ++k) acc[k] += (float)v[k];
      }
      if (i1 < mm) {
        half8 v = *(const half8*)&hp[(size_t)s1 * 64 + fl];
#pragma unroll
        for (int k = 0; k < 8; ++k) acc[k] += (float)v[k];
      }
      if (i2 < mm) {
        half8 v = *(const half8*)&hp[(size_t)s2 * 64 + fl];
#pragma unroll
        for (int k = 0; k < 8; ++k) acc[k] += (float)v[k];
      }
      if (i3 < mm) {
        half8 v = *(const half8*)&hp[(size_t)s3 * 64 + fl];
#pragma unroll
        for (int k = 0; k < 8; ++k) acc[k] += (float)v[k];
      }
    }
  }
#pragma unroll
  for (int o = 8; o < 64; o <<= 1) {
#pragma unroll
    for (int k = 0; k < 8; ++k) acc[k] += __shfl_xor(acc[k], o);
  }
  half8 sv = *(const half8*)&hp[(size_t)wid * 64 + fl];
  float di = dinv[wid];
  float v[8];
#pragma unroll
  for (int k = 0; k < 8; ++k) v[k] = di * (acc[k] + (float)sv[k]);
  if (EPI == 0) {
    if (lane < 8) {
      half8 o;
#pragma unroll
      for (int k = 0; k < 8; ++k) o[k] = (_Float16)v[k];
      *(half8*)&((_Float16*)outp)[(size_t)wid * 64 + fl] = o;
    }
  } else {
    float4 ba = *(const float4*)&bias[fl];
    float4 bb = *(const float4*)&bias[fl + 4];
    v[0] += ba.x; v[1] += ba.y; v[2] += ba.z; v[3] += ba.w;
    v[4] += bb.x; v[5] += bb.y; v[6] += bb.z; v[7] += bb.w;
    float mx = v[0];
#pragma unroll
    for (int k = 1; k < 8; ++k) mx = fmaxf(mx, v[k]);
#pragma unroll
    for (int o = 1; o < 8; o <<= 1) mx = fmaxf(mx, __shfl_xor(mx, o));
    float s = 0.f;
#pragma unroll
    for (int k = 0; k < 8; ++k) {
      v[k] = expf(v[k] - mx);
      s += v[k];
    }
#pragma unroll
    for (int o = 1; o < 8; o <<= 1) s += __shfl_xor(s, o);
    float inv = 1.0f / s;
#pragma unroll
    for (int k = 0; k < 8; ++k) v[k] *= inv;
    if (lane < 8) {
      float4 o0 = make_float4(v[0], v[1], v[2], v[3]);
      float4 o1 = make_float4(v[4], v[5], v[6], v[7]);
      *(float4*)&((float*)outp)[(size_t)wid * 64 + fl] = o0;
      *(float4*)&((float*)outp)[(size_t)wid * 64 + fl + 4] = o1;
    }
  }
}

// F=128: 4 edge-groups x 16 lanes x 8 halves (16B); 4x unroll; fp16 output.
__global__ __launch_bounds__(256) void k_agg128h(const _Float16* __restrict__ hp,
                                                 const float* __restrict__ dinv,
                                                 const int* __restrict__ rowptr,
                                                 const int* __restrict__ col,
                                                 _Float16* __restrict__ out, int N) {
  int wid = blockIdx.x * 4 + (threadIdx.x >> 6);
  int lane = threadIdx.x & 63;
  if (wid >= N) return;
  int g = lane >> 4;
  int fl = (lane & 15) * 8;
  float acc[8] = {0.f, 0.f, 0.f, 0.f, 0.f, 0.f, 0.f, 0.f};
  int r0 = rowptr[wid], r1 = rowptr[wid + 1];
  for (int base = r0; base < r1; base += 64) {
    int mm = min(64, r1 - base);
    int ce = (base + lane < r1) ? col[base + lane] : 0;
    for (int j = 0; j < mm; j += 16) {
      int i0 = j + g, i1 = j + 4 + g, i2 = j + 8 + g, i3 = j + 12 + g;
      int s0 = __shfl(ce, i0), s1 = __shfl(ce, i1);
      int s2 = __shfl(ce, i2), s3 = __shfl(ce, i3);
      if (i0 < mm) {
        half8 v = *(const half8*)&hp[(size_t)s0 * 128 + fl];
#pragma unroll
        for (int k = 0; k < 8; ++k) acc[k] += (float)v[k];
      }
      if (i1 < mm) {
        half8 v = *(const half8*)&hp[(size_t)s1 * 128 + fl];
#pragma unroll
        for (int k = 0; k < 8; ++k) acc[k] += (float)v[k];
      }
      if (i2 < mm) {
        half8 v = *(const half8*)&hp[(size_t)s2 * 128 + fl];
#pragma unroll
        for (int k = 0; k < 8; ++k) acc[k] += (float)v[k];
      }
      if (i3 < mm) {
        half8 v = *(const half8*)&hp[(size_t)s3 * 128 + fl];
#pragma unroll
        for (int k = 0; k < 8; ++k) acc[k] += (float)v[k];
      }
    }
  }
#pragma unroll
  for (int o = 16; o < 64; o <<= 1) {
#pragma unroll
    for (int k = 0; k < 8; ++k) acc[k] += __shfl_xor(acc[k], o);
  }
  half8 sv = *(const half8*)&hp[(size_t)wid * 128 + fl];
  float di = dinv[wid];
  if (lane < 16) {
    half8 o;
#pragma unroll
    for (int k = 0; k < 8; ++k) o[k] = (_Float16)(di * (acc[k] + (float)sv[k]));
    *(half8*)&out[(size_t)wid * 128 + fl] = o;
  }
}

// ---------------- MFMA layer kernels (row-major fp16 I/O) ----------------
// W-frag as A operand, row-frag as B: D(lane) = row rb+(lane&15),
// cols nt*16 + (lane>>4)*4 + reg.

// h1 = (half) dinv * relu(A1h @ W1^T + b1)   [N,64] -> [N,128]
__global__ __launch_bounds__(256) void k_mfma1(const _Float16* __restrict__ a1h,
                                               const _Float16* __restrict__ w1h,  // [128][64]
                                               const float* __restrict__ b1,
                                               const float* __restrict__ dinv,
                                               _Float16* __restrict__ h1, int N) {
  int wave = threadIdx.x >> 6, lane = threadIdx.x & 63;
  int rb = blockIdx.x * 128 + wave * 32;
  if (rb >= N) return;
  int lrow = lane & 15, lg = lane >> 4;

  half8 arow[2][2];
#pragma unroll
  for (int rt = 0; rt < 2; ++rt) {
    int r = rb + rt * 16 + lrow;
    if (r >= N) r = N - 1;
    const _Float16* p = &a1h[(size_t)r * 64 + lg * 8];
    arow[rt][0] = *(const half8*)p;
    arow[rt][1] = *(const half8*)(p + 32);
  }
  f32x4 acc[2][8];
#pragma unroll
  for (int rt = 0; rt < 2; ++rt)
#pragma unroll
    for (int nt = 0; nt < 8; ++nt) acc[rt][nt] = (f32x4){0.f, 0.f, 0.f, 0.f};

#pragma unroll
  for (int nt = 0; nt < 8; ++nt) {
#pragma unroll
    for (int ks = 0; ks < 2; ++ks) {
      half8 wf = *(const half8*)&w1h[(size_t)(nt * 16 + lrow) * 64 + ks * 32 + lg * 8];
      acc[0][nt] = __builtin_amdgcn_mfma_f32_16x16x32_f16(wf, arow[0][ks], acc[0][nt], 0, 0, 0);
      acc[1][nt] = __builtin_amdgcn_mfma_f32_16x16x32_f16(wf, arow[1][ks], acc[1][nt], 0, 0, 0);
    }
  }
#pragma unroll
  for (int rt = 0; rt < 2; ++rt) {
    int r = rb + rt * 16 + lrow;
    if (r < N) {
      float di = dinv[r];
#pragma unroll
      for (int nt = 0; nt < 8; ++nt) {
        int n = nt * 16 + lg * 4;
        float4 bb = *(const float4*)&b1[n];
        half4 o;
        o[0] = (_Float16)(fmaxf(acc[rt][nt][0] + bb.x, 0.f) * di);
        o[1] = (_Float16)(fmaxf(acc[rt][nt][1] + bb.y, 0.f) * di);
        o[2] = (_Float16)(fmaxf(acc[rt][nt][2] + bb.z, 0.f) * di);
        o[3] = (_Float16)(fmaxf(acc[rt][nt][3] + bb.w, 0.f) * di);
        *(half4*)&h1[(size_t)r * 128 + n] = o;
      }
    }
  }
}

// hz = (half) dinv * ( relu(A2h @ W2^T + b2) @ W3^T )   [N,128] -> [N,64]
__global__ __launch_bounds__(256) void k_mfma23(const _Float16* __restrict__ a2h,
                                                const _Float16* __restrict__ w2h,  // [128][128]
                                                const float* __restrict__ b2,
                                                const _Float16* __restrict__ w3h,  // [64][128]
                                                const float* __restrict__ dinv,
                                                _Float16* __restrict__ hz, int N) {
  __shared__ _Float16 u_lds[4][32][136];
  int wave = threadIdx.x >> 6, lane = threadIdx.x & 63;
  int rb = blockIdx.x * 128 + wave * 32;
  if (rb >= N) return;
  int lrow = lane & 15, lg = lane >> 4;

  half8 frag[2][4];
#pragma unroll
  for (int rt = 0; rt < 2; ++rt) {
    int r = rb + rt * 16 + lrow;
    if (r >= N) r = N - 1;
    const _Float16* p = &a2h[(size_t)r * 128 + lg * 8];
#pragma unroll
    for (int ks = 0; ks < 4; ++ks) frag[rt][ks] = *(const half8*)(p + ks * 32);
  }
  f32x4 acc[2][8];
#pragma unroll
  for (int rt = 0; rt < 2; ++rt)
#pragma unroll
    for (int nt = 0; nt < 8; ++nt) acc[rt][nt] = (f32x4){0.f, 0.f, 0.f, 0.f};

#pragma unroll
  for (int nt = 0; nt < 8; ++nt) {
#pragma unroll
    for (int ks = 0; ks < 4; ++ks) {
      half8 wf = *(const half8*)&w2h[(size_t)(nt * 16 + lrow) * 128 + ks * 32 + lg * 8];
      acc[0][nt] = __builtin_amdgcn_mfma_f32_16x16x32_f16(wf, frag[0][ks], acc[0][nt], 0, 0, 0);
      acc[1][nt] = __builtin_amdgcn_mfma_f32_16x16x32_f16(wf, frag[1][ks], acc[1][nt], 0, 0, 0);
    }
  }
#pragma unroll
  for (int rt = 0; rt < 2; ++rt) {
#pragma unroll
    for (int nt = 0; nt < 8; ++nt) {
      int n = nt * 16 + lg * 4;
      float4 bb = *(const float4*)&b2[n];
      half4 o;
      o[0] = (_Float16)fmaxf(acc[rt][nt][0] + bb.x, 0.f);
      o[1] = (_Float16)fmaxf(acc[rt][nt][1] + bb.y, 0.f);
      o[2] = (_Float16)fmaxf(acc[rt][nt][2] + bb.z, 0.f);
      o[3] = (_Float16)fmaxf(acc[rt][nt][3] + bb.w, 0.f);
      *(half4*)&u_lds[wave][rt * 16 + lrow][n] = o;
    }
  }
#pragma unroll
  for (int rt = 0; rt < 2; ++rt)
#pragma unroll
    for (int ks = 0; ks < 4; ++ks)
      frag[rt][ks] = *(const half8*)&u_lds[wave][rt * 16 + lrow][ks * 32 + lg * 8];

  f32x4 acc2[2][4];
#pragma unroll
  for (int rt = 0; rt < 2; ++rt)
#pragma unroll
    for (int mt = 0; mt < 4; ++mt) acc2[rt][mt] = (f32x4){0.f, 0.f, 0.f, 0.f};

#pragma unroll
  for (int mt = 0; mt < 4; ++mt) {
#pragma unroll
    for (int ks = 0; ks < 4; ++ks) {
      half8 wf = *(const half8*)&w3h[(size_t)(mt * 16 + lrow) * 128 + ks * 32 + lg * 8];
      acc2[0][mt] = __builtin_amdgcn_mfma_f32_16x16x32_f16(wf, frag[0][ks], acc2[0][mt], 0, 0, 0);
      acc2[1][mt] = __builtin_amdgcn_mfma_f32_16x16x32_f16(wf, frag[1][ks], acc2[1][mt], 0, 0, 0);
    }
  }
#pragma unroll
  for (int rt = 0; rt < 2; ++rt) {
    int r = rb + rt * 16 + lrow;
    if (r < N) {
      float di = dinv[r];
#pragma unroll
      for (int mt = 0; mt < 4; ++mt) {
        int m = mt * 16 + lg * 4;
        half4 o;
        o[0] = (_Float16)(acc2[rt][mt][0] * di);
        o[1] = (_Float16)(acc2[rt][mt][1] * di);
        o[2] = (_Float16)(acc2[rt][mt][2] * di);
        o[3] = (_Float16)(acc2[rt][mt][3] * di);
        *(half4*)&hz[(size_t)r * 64 + m] = o;
      }
    }
  }
}

// ---------------- launch ----------------

extern "C" void kernel_launch(void* const* d_in, const int* in_sizes, int n_in,
                              void* d_out, int out_size, void* d_ws, size_t ws_size,
                              hipStream_t stream) {
  const float* x  = (const float*)d_in[0];
  const int*   ei = (const int*)d_in[1];
  const float* W1 = (const float*)d_in[2];
  const float* b1 = (const float*)d_in[3];
  const float* W2 = (const float*)d_in[4];
  const float* b2 = (const float*)d_in[5];
  const float* W3 = (const float*)d_in[6];
  const float* b3 = (const float*)d_in[7];
  float* out = (float*)d_out;

  const int N = in_sizes[0] / 64;
  const int E = in_sizes[1] / 2;
  const int* esrc = ei;
  const int* edst = ei + E;

  const int NBUK = (N + 255) / 256;
  const int C1 = (E + NB1 - 1) / NB1;
  const int L = NBUK * NB1;
  const int NA = (L + 255) / 256;

  char* w = (char*)d_ws;
  auto take = [&](size_t bytes) -> void* {
    void* p = (void*)w;
    w += (bytes + 255) & ~(size_t)255;
    return p;
  };
  int*   rowptr = (int*)take((size_t)(N + 1) * 4);
  float* dinv   = (float*)take((size_t)N * 4);
  int*   col    = (int*)take((size_t)E * 4);
  int*   gh     = (int*)take((size_t)L * 4);
  int*   gscan  = (int*)take((size_t)L * 4);
  int*   part   = (int*)take((size_t)NA * 4);
  _Float16* w1h = (_Float16*)take((size_t)128 * 64 * 2);
  _Float16* w2h = (_Float16*)take((size_t)128 * 128 * 2);
  _Float16* w3h = (_Float16*)take((size_t)64 * 128 * 2);
  _Float16* hx  = (_Float16*)take((size_t)N * 64 * 2);   // prescaled x; reused as hz
  _Float16* a1h = (_Float16*)take((size_t)N * 64 * 2);   // agg(x) fp16
  _Float16* h1  = (_Float16*)take((size_t)N * 128 * 2);  // h1p; epak aliases (dead before)
  _Float16* a2h = (_Float16*)take((size_t)N * 128 * 2);  // agg(h1) fp16
  int*   epak   = (int*)h1;   // dead before h1's first write
  _Float16* hz  = hx;         // x-table dead after layer-1 agg

  // CSR build (no global atomics); weights fp16 ride along in k_hist
  k_hist<<<NB1 + 128, 256, 0, stream>>>(edst, E, C1, NBUK, gh, W1, W2, W3, w1h, w2h, w3h);
  k_sum256<<<NA, 256, 0, stream>>>(gh, L, part);
  k_scan_apply<<<NA, 256, 0, stream>>>(gh, L, part, NA, gscan);
  k_scatter<<<NB1, 256, 0, stream>>>(esrc, edst, E, C1, NBUK, gscan, epak);
  k_csr<<<NBUK, 256, 0, stream>>>(epak, gscan, NBUK, N, E, rowptr, dinv, col, x, hx);

  const int aggblocks = (N + 3) / 4;
  const int mfmablocks = (N + 127) / 128;

  // A1h = (half) agg(hx)
  k_agg64h<0><<<aggblocks, 256, 0, stream>>>(hx, dinv, rowptr, col, nullptr, a1h, N);
  // h1 = (half) dinv * relu(A1h @ W1^T + b1)
  k_mfma1<<<mfmablocks, 256, 0, stream>>>(a1h, w1h, b1, dinv, h1, N);
  // A2h = (half) agg(h1)
  k_agg128h<<<aggblocks, 256, 0, stream>>>(h1, dinv, rowptr, col, a2h, N);
  // hz = (half) dinv * (relu(A2h @ W2^T + b2) @ W3^T)
  k_mfma23<<<mfmablocks, 256, 0, stream>>>(a2h, w2h, b2, w3h, dinv, hz, N);
  // out = softmax(agg(hz) + b3)
  k_agg64h<1><<<aggblocks, 256, 0, stream>>>(hz, dinv, rowptr, col, b3, out, N);
}